// Round 17
// baseline (505.371 us; speedup 1.0000x reference)
//
#include <hip/hip_runtime.h>
#include <cstdint>
#include <cstddef>

// ---------------- problem constants ----------------
#define T_SEQ 2048
#define C_DIM 1024
#define H_HEADS 16
#define D_HEAD 64
#define FF_DIM 4096
#define V_VOCAB 32000
#define L_LAYERS 2

typedef unsigned short u16;
typedef short bf16x8 __attribute__((ext_vector_type(8)));
typedef float f32x4 __attribute__((ext_vector_type(4)));

__device__ inline u16 f2bf(float f) {
  unsigned u = __float_as_uint(f);
  u += 0x7fffu + ((u >> 16) & 1u);   // RNE
  return (u16)(u >> 16);
}
__device__ inline float bf2f(u16 h) { return __uint_as_float(((unsigned)h) << 16); }

// ---------------- device arena ----------------
#define OFF_WTEBF   0ULL                    // 32000*1024 bf16
#define OFF_ATTNBF  65536000ULL             // 2*2048*1024 bf16
#define OFF_FCBF    73924608ULL             // 2*4096*1024 bf16
#define OFF_PRJBF   90701824ULL             // 2*1024*4096 bf16
#define OFF_X       107479040ULL            // 2048*1024 f32 (residual stream)
#define OFF_HBF     115867648ULL            // 2048*1024 bf16 (LN out)
#define OFF_QKBF    120061952ULL            // 2048*2048 bf16 (q|k)
#define OFF_VT      128450560ULL            // 16*64*2048 bf16 (V^T per head)
#define OFF_FBF     141033472ULL            // 2048*4096 bf16 (gelu(fc) out)
#define OFF_VWBF    157810688ULL            // 2*16*64*64 bf16 (v_tmp)
#define OFF_PWBF    158072832ULL            // 2*16*64*64 bf16 (proj_tmp)
#define ARENA_BYTES 158334976ULL

__device__ __align__(1024) unsigned char g_arena[ARENA_BYTES];

// ---------------- fused cvt(all weights) + embed+LN1 ------------------------
__global__ void cvt_embed_k(const float4* __restrict__ sw, const float4* __restrict__ s0,
                            const float4* __restrict__ s1, const float4* __restrict__ s2,
                            const float4* __restrict__ s3, const float4* __restrict__ s4,
                            ushort4* __restrict__ dw, ushort4* __restrict__ d0,
                            ushort4* __restrict__ d1, ushort4* __restrict__ d2,
                            ushort4* __restrict__ d3, ushort4* __restrict__ d4,
                            const int* __restrict__ idx, float4* __restrict__ x,
                            const float* __restrict__ lw, const float* __restrict__ lb,
                            ushort4* __restrict__ hout) {
  int blk = blockIdx.x, tid = threadIdx.x;
  if (blk < 52736) {
    int g = blk * 256 + tid;
    const float4* s; ushort4* d; int off;
    if (g < 8192000)       { s = sw; d = dw; off = g; }
    else {
      int g2 = g - 8192000;
      if (g2 < 1048576)      { s = s0; d = d0; off = g2; }
      else if (g2 < 3145728) { s = s1; d = d1; off = g2 - 1048576; }
      else if (g2 < 5242880) { s = s2; d = d2; off = g2 - 3145728; }
      else if (g2 < 5275648) { s = s3; d = d3; off = g2 - 5242880; }
      else                   { s = s4; d = d4; off = g2 - 5275648; }
    }
    float4 v = s[off];
    d[off] = make_ushort4(f2bf(v.x), f2bf(v.y), f2bf(v.z), f2bf(v.w));
  } else {
    int t = blk - 52736;
    int r = idx[t];
    float4 v = sw[(size_t)r * 256 + tid];
    x[(size_t)t * 256 + tid] = v;
    float s = v.x + v.y + v.z + v.w;
    float s2 = v.x * v.x + v.y * v.y + v.z * v.z + v.w * v.w;
    #pragma unroll
    for (int m = 1; m <= 8; m <<= 1) { s += __shfl_xor(s, m); s2 += __shfl_xor(s2, m); }
    int h = tid >> 4;
    float mu = s * (1.f / 64.f), var = s2 * (1.f / 64.f) - mu * mu;
    float rs = rsqrtf(var + 1e-5f) * lw[h], b = lb[h];
    hout[(size_t)t * 256 + tid] =
        make_ushort4(f2bf((v.x - mu) * rs + b), f2bf((v.y - mu) * rs + b),
                     f2bf((v.z - mu) * rs + b), f2bf((v.w - mu) * rs + b));
  }
}

// ---------------- generic swizzled global->LDS staging ----------------
template <int NROWS, int ROWBYTES, int WAVES>
__device__ inline void stage_rows(u16* lds, const u16* __restrict__ g, int ld,
                                  int wid, int lane) {
  constexpr int PASSES = (NROWS * ROWBYTES) / (WAVES * 1024);
  #pragma unroll
  for (int i = 0; i < PASSES; i++) {
    int base = (i * WAVES + wid) * 1024;          // wave-uniform LDS byte base
    int o = base + lane * 16;                     // this lane's linear dest
    int u = o ^ (((o / ROWBYTES) & 7) << 4);      // un-swizzled byte addr
    int row = u / ROWBYTES, colb = u % ROWBYTES;
    const u16* src = g + (size_t)row * ld + (colb >> 1);
    __builtin_amdgcn_global_load_lds((const __attribute__((address_space(1))) void*)src,
                                     (__attribute__((address_space(3))) void*)(lds + base / 2),
                                     16, 0, 0);
  }
}

// ---------------- flash attention v7.2 (exp2 softmax + T5 setprio) ---------
__global__ __launch_bounds__(256) void flash_k(const u16* __restrict__ qk,
                                               const u16* __restrict__ vt,
                                               const u16* __restrict__ pw,
                                               float* __restrict__ x,
                                               const float* __restrict__ ln2w,
                                               const float* __restrict__ ln2b,
                                               u16* __restrict__ hout) {
  int h = blockIdx.y;
  int q0 = blockIdx.x * 64;
  int tid = threadIdx.x, wid = tid >> 6, lane = tid & 63;
  int g4 = lane >> 4, l15 = lane & 15;
  __shared__ u16 Kl[128 * 64];    // [key][d]    rowbytes 128, swizzled
  __shared__ u16 Vl[64 * 128];    // [d][key]    rowbytes 256, swizzled
  __shared__ u16 Pl[64 * 128];    // [qrow][key] rowbytes 256, wave-private rows
  // exp2-folded constants: exp(v) = exp2(v*log2e)
  float slopeL = exp2f(-0.5f * (float)(h + 1)) * 1.44269504f;

  bf16x8 qf[2];
  const u16* qb = qk + (size_t)(q0 + wid * 16) * 2048 + h * 64;
  #pragma unroll
  for (int kk = 0; kk < 2; kk++)
    qf[kk] = *(const bf16x8*)(qb + (size_t)l15 * 2048 + kk * 32 + g4 * 8);

  float lsum = 0.f;
  f32x4 oacc[4];
  #pragma unroll
  for (int n = 0; n < 4; n++) oacc[n] = (f32x4){0.f, 0.f, 0.f, 0.f};

  const u16* kbase = qk + 1024 + h * 64;
  const u16* vbase = vt + (size_t)h * 64 * T_SEQ;
  int myq = q0 + wid * 16 + l15;

  for (int kt = 0; kt < T_SEQ / 128; kt++) {
    int k0 = kt * 128;
    stage_rows<128, 128, 4>(Kl, kbase + (size_t)k0 * 2048, 2048, wid, lane);
    stage_rows<64, 256, 4>(Vl, vbase + k0, T_SEQ, wid, lane);
    __syncthreads();

    // S^T = K Q^T  (swapped: lane: q=l15, key=n*16+g4*4+i)
    f32x4 s[8];
    #pragma unroll
    for (int n = 0; n < 8; n++) s[n] = (f32x4){0.f, 0.f, 0.f, 0.f};
    __builtin_amdgcn_s_setprio(1);
    #pragma unroll
    for (int kk = 0; kk < 2; kk++) {
      #pragma unroll
      for (int n = 0; n < 8; n++) {
        int r = n * 16 + l15;
        int b = (r * 128 + kk * 64 + g4 * 16) ^ ((r & 7) << 4);
        bf16x8 kf = *(const bf16x8*)((const char*)Kl + b);
        s[n] = __builtin_amdgcn_mfma_f32_16x16x32_bf16(kf, qf[kk], s[n], 0, 0, 0);
      }
    }
    __builtin_amdgcn_s_setprio(0);

    // softmax: p = exp2(s*(0.125*log2e) + slopeL*min(key-q,0) - 8*log2e)
    float fd = (float)(k0 + g4 * 4 - myq);
    int pr = wid * 16 + l15;
    #pragma unroll
    for (int n = 0; n < 8; n++) {
      float p[4];
      #pragma unroll
      for (int i = 0; i < 4; i++) {
        float dj = fd + (float)(n * 16 + i);
        float a2 = fmaf(slopeL, fminf(dj, 0.f), -11.54156036f);
        p[i] = exp2f(fmaf(s[n][i], 0.18033688f, a2));
        lsum += p[i];
      }
      unsigned lo, hi;
      asm("v_cvt_pk_bf16_f32 %0, %1, %2" : "=v"(lo) : "v"(p[0]), "v"(p[1]));
      asm("v_cvt_pk_bf16_f32 %0, %1, %2" : "=v"(hi) : "v"(p[2]), "v"(p[3]));
      int b = (pr * 256 + n * 32 + g4 * 8) ^ ((pr & 7) << 4);
      *(uint2*)((char*)Pl + b) = make_uint2(lo, hi);
    }

    // O += P V
    __builtin_amdgcn_s_setprio(1);
    #pragma unroll
    for (int kk = 0; kk < 4; kk++) {
      int pb = (pr * 256 + kk * 64 + g4 * 16) ^ ((pr & 7) << 4);
      bf16x8 pa = *(const bf16x8*)((const char*)Pl + pb);
      #pragma unroll
      for (int n = 0; n < 4; n++) {
        int d = n * 16 + l15;
        int vb = (d * 256 + kk * 64 + g4 * 16) ^ ((d & 7) << 4);
        bf16x8 vf = *(const bf16x8*)((const char*)Vl + vb);
        oacc[n] = __builtin_amdgcn_mfma_f32_16x16x32_bf16(pa, vf, oacc[n], 0, 0, 0);
      }
    }
    __builtin_amdgcn_s_setprio(0);
    __syncthreads();
  }

  // lsum: keys partitioned across g4 groups -> xor-reduce bits 4,5
  lsum += __shfl_xor(lsum, 16);
  lsum += __shfl_xor(lsum, 32);
  float linv[4];
  #pragma unroll
  for (int i = 0; i < 4; i++) linv[i] = 1.f / __shfl(lsum, g4 * 4 + i);

  // ---- fused head-proj: x[q][h*64+e] += O @ pw[h]^T ----
  stage_rows<64, 128, 4>(Kl, pw + (size_t)h * 4096, 64, wid, lane);
  #pragma unroll
  for (int n = 0; n < 4; n++)
    #pragma unroll
    for (int i = 0; i < 4; i++) {
      int pr = wid * 16 + g4 * 4 + i;
      int b = (pr * 256 + (n * 16 + l15) * 2) ^ ((pr & 7) << 4);
      *(u16*)((char*)Pl + b) = f2bf(oacc[n][i] * linv[i]);
    }
  __syncthreads();   // pw staged (implicit vmcnt drain); own-wave O via lgkm

  f32x4 acc2[4];
  #pragma unroll
  for (int n = 0; n < 4; n++) acc2[n] = (f32x4){0.f, 0.f, 0.f, 0.f};
  #pragma unroll
  for (int kk = 0; kk < 2; kk++) {
    int pr = wid * 16 + l15;
    int ab = (pr * 256 + kk * 64 + g4 * 16) ^ ((pr & 7) << 4);
    bf16x8 af = *(const bf16x8*)((const char*)Pl + ab);
    #pragma unroll
    for (int n = 0; n < 4; n++) {
      int r = n * 16 + l15;
      int wb = (r * 128 + kk * 64 + g4 * 16) ^ ((r & 7) << 4);
      bf16x8 wf = *(const bf16x8*)((const char*)Kl + wb);
      acc2[n] = __builtin_amdgcn_mfma_f32_16x16x32_bf16(af, wf, acc2[n], 0, 0, 0);
    }
  }

  // ---- x RMW + fused LN2 -> hout ----
  float* xb = x + (size_t)(q0 + wid * 16) * C_DIM + h * 64;
  u16* hb = hout + (size_t)(q0 + wid * 16) * C_DIM + h * 64;
  float xv[4][4];
  #pragma unroll
  for (int n = 0; n < 4; n++)
    #pragma unroll
    for (int i = 0; i < 4; i++) {
      size_t o = (size_t)(g4 * 4 + i) * C_DIM + n * 16 + l15;
      float t = xb[o] + acc2[n][i];
      xb[o] = t;
      xv[n][i] = t;
    }
  float lw = ln2w[h], lb = ln2b[h];
  #pragma unroll
  for (int i = 0; i < 4; i++) {
    float s = 0.f, s2 = 0.f;
    #pragma unroll
    for (int n = 0; n < 4; n++) { float t = xv[n][i]; s += t; s2 += t * t; }
    #pragma unroll
    for (int m = 1; m <= 8; m <<= 1) { s += __shfl_xor(s, m); s2 += __shfl_xor(s2, m); }
    float mu = s * (1.f / 64.f), var = s2 * (1.f / 64.f) - mu * mu;
    float rs = rsqrtf(var + 1e-5f) * lw;
    #pragma unroll
    for (int n = 0; n < 4; n++)
      hb[(size_t)(g4 * 4 + i) * C_DIM + n * 16 + l15] = f2bf((xv[n][i] - mu) * rs + lb);
  }
}

// ---------------- 256x256 counted-vmcnt pipelined GEMM (lm_head) ------------
// r17: the one untested schedule combo. Per K-tile: issue ALL of tile t+1's
// 8 gloads at tile entry, THEN counted vmcnt(8) (tile t's 8 older loads
// retire; t+1's stay in flight ACROSS the barrier -> pipe never drains; cf.
// m218: counted-vs-drain0 is the T4 lever), s_barrier, then 4 lean phases
// {reads | setprio MFMA | barrier}. WAR: buf[(t+1)&1]'s readers (iter t-1)
// finished before t-1's last phase barrier < our staging issue. RAW: own
// vmcnt(8) + s_barrier => all waves' tile-t staging visible.
#define ASM_VMCNT8 asm volatile("s_waitcnt vmcnt(8)" ::: "memory")
#define ASM_VMCNT0 asm volatile("s_waitcnt vmcnt(0)" ::: "memory")

__global__ __launch_bounds__(512, 1) void gemm256_k(const u16* __restrict__ A, int lda,
                                                    const u16* __restrict__ B, int ldb,
                                                    float* __restrict__ C, int ldc,
                                                    int K, int MT) {
  extern __shared__ u16 sm[];
  u16* lsA = sm;              // [2][256*64] u16
  u16* lsB = sm + 32768;      // [2][256*64] u16
  int tid = threadIdx.x, wid = tid >> 6, lane = tid & 63;
  int g4 = lane >> 4, l15 = lane & 15;
  int wm = wid >> 2, wn = wid & 3;
  int nwg = gridDim.x, lin = blockIdx.x;
  int chunk = nwg >> 3;                       // nwg % 8 == 0 (bijective)
  int w = (lin & 7) * chunk + (lin >> 3);     // XCD gets contiguous chunk
  int by = w % MT, bx = w / MT;               // M-fast -> B-panel reuse
  const u16* Ab = A + (size_t)(by * 256) * lda;
  const u16* Bb = B + (size_t)(bx * 256) * ldb;

  f32x4 acc[8][4];
  #pragma unroll
  for (int m = 0; m < 8; m++)
    #pragma unroll
    for (int n = 0; n < 4; n++) acc[m][n] = (f32x4){0.f, 0.f, 0.f, 0.f};

  int NT = K >> 6;
  // prologue: stage K-tile 0 into buf 0
  stage_rows<256, 128, 8>(lsA, Ab, lda, wid, lane);
  stage_rows<256, 128, 8>(lsB, Bb, ldb, wid, lane);

  for (int t = 0; t < NT; ++t) {
    int cur = t & 1;
    const char* cA = (const char*)(lsA + cur * 16384);
    const char* cB = (const char*)(lsB + cur * 16384);

    if (t + 1 < NT) {
      // issue tile t+1's 8 loads FIRST, then counted wait: tile t's (older)
      // loads retire, t+1's 8 stay in flight across the barrier.
      stage_rows<256, 128, 8>(lsA + (cur ^ 1) * 16384, Ab + (t + 1) * 64, lda, wid, lane);
      stage_rows<256, 128, 8>(lsB + (cur ^ 1) * 16384, Bb + (t + 1) * 64, ldb, wid, lane);
      ASM_VMCNT8;
    } else {
      ASM_VMCNT0;
    }
    __builtin_amdgcn_s_barrier();            // all waves' tile-t staging visible
    __builtin_amdgcn_sched_barrier(0);       // no motion across the buffer swap

    bf16x8 bfr[4], af[4];
    #pragma unroll
    for (int ph = 0; ph < 4; ++ph) {
      const int kk = ph >> 1, mh = ph & 1;
      if (mh == 0) {
        #pragma unroll
        for (int n = 0; n < 4; n++) {
          int r = wn * 64 + n * 16 + l15;
          bfr[n] = *(const bf16x8*)(cB + ((r * 128 + kk * 64 + g4 * 16) ^ ((r & 7) << 4)));
        }
      }
      #pragma unroll
      for (int m = 0; m < 4; m++) {
        int r = wm * 128 + mh * 64 + m * 16 + l15;
        af[m] = *(const bf16x8*)(cA + ((r * 128 + kk * 64 + g4 * 16) ^ ((r & 7) << 4)));
      }
      __builtin_amdgcn_s_setprio(1);
      #pragma unroll
      for (int m = 0; m < 4; m++)            // compiler inserts counted lgkm waits
        #pragma unroll
        for (int n = 0; n < 4; n++)
          acc[mh * 4 + m][n] =
              __builtin_amdgcn_mfma_f32_16x16x32_bf16(af[m], bfr[n], acc[mh * 4 + m][n], 0, 0, 0);
      __builtin_amdgcn_s_setprio(0);
      __builtin_amdgcn_s_barrier();          // phase lockstep; last guards WAR
    }
  }

  int gr0 = by * 256 + wm * 128, gc0 = bx * 256 + wn * 64;
  #pragma unroll
  for (int m = 0; m < 8; m++)
    #pragma unroll
    for (int n = 0; n < 4; n++)
      #pragma unroll
      for (int i = 0; i < 4; i++)
        C[(size_t)(gr0 + m * 16 + g4 * 4 + i) * ldc + gc0 + n * 16 + l15] = acc[m][n][i];
}

// ---------------- bf16 NT GEMM body (device fn; LDS passed in) --------------
// EPI: 1=bias+bf16, 2=bf16, 3=bias+gelu+bf16,
//      6=bias+resid+f32 AND fused per-head LN -> hout (needs RN==64)
template <int BM, int BN, int WM, int WN, int EPI, int MT>
__device__ void gemm_body(u16* lsA, u16* lsB,
                          const u16* __restrict__ A, int lda, long long sA,
                          const u16* __restrict__ B, int ldb, long long sB,
                          void* __restrict__ C, int ldc, long long sC,
                          int K, const float* __restrict__ bias,
                          const float* __restrict__ resid, int ldr,
                          const float* __restrict__ lnw, const float* __restrict__ lnb,
                          u16* __restrict__ hout, int lin, int z) {
  constexpr int RM = BM / WM, RN = BN / WN;
  constexpr int MR = RM / 16, NR = RN / 16;
  int tid = threadIdx.x, wid = tid >> 6, lane = tid & 63;
  int wm = wid / WN, wn = wid % WN;
  int by = lin % MT, bx = lin / MT;
  int row0 = by * BM, col0 = bx * BN;
  const u16* Ab = A + (size_t)z * sA + (size_t)row0 * lda;
  const u16* Bb = B + (size_t)z * sB + (size_t)col0 * ldb;
  size_t cz = (size_t)z * sC;

  f32x4 acc[MR][NR];
  #pragma unroll
  for (int m = 0; m < MR; m++)
    #pragma unroll
    for (int n = 0; n < NR; n++) acc[m][n] = (f32x4){0.f, 0.f, 0.f, 0.f};

  for (int k0 = 0; k0 < K; k0 += 64) {
    stage_rows<BM, 128, 4>(lsA, Ab + k0, lda, wid, lane);
    stage_rows<BN, 128, 4>(lsB, Bb + k0, ldb, wid, lane);
    __syncthreads();
    #pragma unroll
    for (int kk = 0; kk < 2; kk++) {
      bf16x8 af[MR], bfr[NR];
      #pragma unroll
      for (int m = 0; m < MR; m++) {
        int r = wm * RM + m * 16 + (lane & 15);
        int bofs = (r * 128 + kk * 64 + ((lane >> 4) * 16)) ^ ((r & 7) << 4);
        af[m] = *(const bf16x8*)((const char*)lsA + bofs);
      }
      #pragma unroll
      for (int n = 0; n < NR; n++) {
        int r = wn * RN + n * 16 + (lane & 15);
        int bofs = (r * 128 + kk * 64 + ((lane >> 4) * 16)) ^ ((r & 7) << 4);
        bfr[n] = *(const bf16x8*)((const char*)lsB + bofs);
      }
      #pragma unroll
      for (int m = 0; m < MR; m++)
        #pragma unroll
        for (int n = 0; n < NR; n++)
          acc[m][n] = __builtin_amdgcn_mfma_f32_16x16x32_bf16(af[m], bfr[n], acc[m][n], 0, 0, 0);
    }
    __syncthreads();
  }

  int rbase = row0 + wm * RM, cbase = col0 + wn * RN;
  if constexpr (EPI == 6) {
    float vv[MR][NR][4];
    #pragma unroll
    for (int m = 0; m < MR; m++)
      #pragma unroll
      for (int n = 0; n < NR; n++)
        #pragma unroll
        for (int i = 0; i < 4; i++) {
          int gr = rbase + m * 16 + ((lane >> 4) * 4) + i;
          int gc = cbase + n * 16 + (lane & 15);
          float v = acc[m][n][i] + bias[gc] + resid[(size_t)gr * ldr + gc];
          vv[m][n][i] = v;
          ((float*)C)[(size_t)gr * ldc + gc] = v;
        }
    int h = cbase >> 6;
    float lw = lnw[h], lb = lnb[h];
    #pragma unroll
    for (int m = 0; m < MR; m++)
      #pragma unroll
      for (int i = 0; i < 4; i++) {
        float s = 0.f, s2 = 0.f;
        #pragma unroll
        for (int n = 0; n < NR; n++) { float t = vv[m][n][i]; s += t; s2 += t * t; }
        #pragma unroll
        for (int msk = 1; msk <= 8; msk <<= 1) { s += __shfl_xor(s, msk); s2 += __shfl_xor(s2, msk); }
        float mu = s * (1.f / 64.f), var = s2 * (1.f / 64.f) - mu * mu;
        float rs = rsqrtf(var + 1e-5f) * lw;
        int gr = rbase + m * 16 + ((lane >> 4) * 4) + i;
        #pragma unroll
        for (int n = 0; n < NR; n++) {
          int gc = cbase + n * 16 + (lane & 15);
          hout[(size_t)gr * C_DIM + gc] = f2bf((vv[m][n][i] - mu) * rs + lb);
        }
      }
  } else {
    #pragma unroll
    for (int m = 0; m < MR; m++)
      #pragma unroll
      for (int n = 0; n < NR; n++)
        #pragma unroll
        for (int i = 0; i < 4; i++) {
          int gr = rbase + m * 16 + ((lane >> 4) * 4) + i;
          int gc = cbase + n * 16 + (lane & 15);
          size_t idx = cz + (size_t)gr * ldc + gc;
          float v = acc[m][n][i];
          if constexpr (EPI == 1) {
            v += bias[gc];
            ((u16*)C)[idx] = f2bf(v);
          } else if constexpr (EPI == 2) {
            ((u16*)C)[idx] = f2bf(v);
          } else if constexpr (EPI == 3) {
            v += bias[gc];
            v = 0.5f * v * (1.f + erff(v * 0.70710678118654752f));
            ((u16*)C)[idx] = f2bf(v);
          }
        }
  }
}

// standalone GEMM wrapper (M-fast 1D grid + bijective XCD chunk, z=0)
template <int BM, int BN, int WM, int WN, int EPI, int MT>
__global__ void gemm_nt(const u16* __restrict__ A, int lda,
                        const u16* __restrict__ B, int ldb,
                        void* __restrict__ C, int ldc,
                        int K, const float* __restrict__ bias,
                        const float* __restrict__ resid, int ldr,
                        const float* __restrict__ lnw, const float* __restrict__ lnb,
                        u16* __restrict__ hout) {
  __shared__ u16 lsA[BM * 64];
  __shared__ u16 lsB[BN * 64];
  int nwg = gridDim.x, l0 = blockIdx.x;
  int chunk = nwg >> 3;
  int lin = (l0 & 7) * chunk + (l0 >> 3);
  gemm_body<BM, BN, WM, WN, EPI, MT>(lsA, lsB, A, lda, 0, B, ldb, 0, C, ldc, 0,
                                     K, bias, resid, ldr, lnw, lnb, hout, lin, 0);
}

// merged qk + vt launch: blocks [0,512) qk GEMM, [512,768) per-head vt GEMM
__global__ void qkv_k(const u16* __restrict__ hbf, const u16* __restrict__ attw,
                      const float* __restrict__ attb, u16* __restrict__ qkbf,
                      const u16* __restrict__ vw, u16* __restrict__ vt) {
  __shared__ u16 lsA[64 * 64];
  __shared__ u16 lsB[128 * 64];
  int l0 = blockIdx.x;
  if (l0 < 512) {
    int lin = (l0 & 7) * 64 + (l0 >> 3);          // XCD chunk over 512
    gemm_body<64, 128, 2, 2, 1, 32>(lsA, lsB, hbf, C_DIM, 0, attw, C_DIM, 0,
                                    qkbf, 2 * C_DIM, 0, C_DIM, attb, nullptr, 0,
                                    nullptr, nullptr, nullptr, lin, 0);
  } else {
    int i2 = l0 - 512;                             // 256 blocks: 16 tiles x 16 heads
    gemm_body<64, 128, 2, 2, 2, 1>(lsA, lsB, vw, 64, 4096, hbf, C_DIM, 64,
                                   vt, T_SEQ, (long long)64 * T_SEQ, 64,
                                   nullptr, nullptr, 0, nullptr, nullptr, nullptr,
                                   i2 & 15, i2 >> 4);
  }
}

// ---------------- host launch ----------------
extern "C" void kernel_launch(void* const* d_in, const int* in_sizes, int n_in,
                              void* d_out, int out_size, void* d_ws, size_t ws_size,
                              hipStream_t stream) {
  (void)in_sizes; (void)n_in; (void)out_size; (void)d_ws; (void)ws_size;
  const int*   idx    = (const int*)d_in[0];
  const float* wte    = (const float*)d_in[1];
  const float* ln1w   = (const float*)d_in[2];
  const float* ln1b   = (const float*)d_in[3];
  const float* ln2w   = (const float*)d_in[4];
  const float* ln2b   = (const float*)d_in[5];
  const float* lnfw   = (const float*)d_in[6];
  const float* lnfb   = (const float*)d_in[7];
  const float* attw   = (const float*)d_in[8];
  const float* attb   = (const float*)d_in[9];
  const float* vtmp   = (const float*)d_in[10];
  const float* ptmp   = (const float*)d_in[11];
  const float* fcw    = (const float*)d_in[12];
  const float* fcb    = (const float*)d_in[13];
  const float* prjw   = (const float*)d_in[14];
  const float* prjb   = (const float*)d_in[15];
  float* out = (float*)d_out;

  unsigned char* ar = nullptr;
  (void)hipGetSymbolAddress((void**)&ar, HIP_SYMBOL(g_arena));
  u16*   wtebf  = (u16*)(ar + OFF_WTEBF);
  u16*   attnbf = (u16*)(ar + OFF_ATTNBF);
  u16*   fcbf   = (u16*)(ar + OFF_FCBF);
  u16*   prjbf  = (u16*)(ar + OFF_PRJBF);
  float* x      = (float*)(ar + OFF_X);
  u16*   hbf    = (u16*)(ar + OFF_HBF);
  u16*   qkbf   = (u16*)(ar + OFF_QKBF);
  u16*   vt     = (u16*)(ar + OFF_VT);
  u16*   fbf    = (u16*)(ar + OFF_FBF);
  u16*   vwbf   = (u16*)(ar + OFF_VWBF);
  u16*   pwbf   = (u16*)(ar + OFF_PWBF);

  (void)hipFuncSetAttribute((const void*)gemm256_k,
                            hipFuncAttributeMaxDynamicSharedMemorySize, 131072);

  // weight cvt + embed+LN1 in ONE launch (embed blocks appended after cvt)
  cvt_embed_k<<<dim3(52736 + T_SEQ), 256, 0, stream>>>(
      (const float4*)wte, (const float4*)attw, (const float4*)fcw,
      (const float4*)prjw, (const float4*)vtmp, (const float4*)ptmp,
      (ushort4*)wtebf, (ushort4*)attnbf, (ushort4*)fcbf,
      (ushort4*)prjbf, (ushort4*)vwbf, (ushort4*)pwbf,
      idx, (float4*)x, ln1w, ln1b, (ushort4*)hbf);

  for (int l = 0; l < L_LAYERS; l++) {
    // qk GEMM + per-head vt GEMM in one launch (768 blocks, 3/CU)
    qkv_k<<<dim3(768), 256, 0, stream>>>(
        hbf, attnbf + (size_t)l * 2 * C_DIM * C_DIM, attb + l * 2 * C_DIM, qkbf,
        vwbf + (size_t)l * H_HEADS * 4096, vt);
    // flash attention + head-proj (x +=) + LN2 -> hbf
    flash_k<<<dim3(T_SEQ / 64, H_HEADS), 256, 0, stream>>>(
        qkbf, vt, pwbf + (size_t)l * H_HEADS * 4096, x,
        ln2w + l * H_HEADS, ln2b + l * H_HEADS, hbf);
    // f = gelu(LN2(x) @ fc_w^T + fc_b) -> bf16  (1024 blocks, 4/CU)
    gemm_nt<64, 128, 2, 2, 3, 32><<<dim3((FF_DIM / 128) * (T_SEQ / 64)), 256, 0, stream>>>(
        hbf, C_DIM, fcbf + (size_t)l * FF_DIM * C_DIM, C_DIM,
        fbf, FF_DIM, C_DIM, fcb + l * FF_DIM, nullptr, 0,
        nullptr, nullptr, nullptr);
    // x = x + f @ proj_w^T + proj_b  AND fused LN (next LN1 / LNf)
    const float* nw = (l + 1 < L_LAYERS) ? ln1w + (l + 1) * H_HEADS : lnfw;
    const float* nb = (l + 1 < L_LAYERS) ? ln1b + (l + 1) * H_HEADS : lnfb;
    gemm_nt<32, 128, 2, 2, 6, 64><<<dim3((C_DIM / 128) * (T_SEQ / 32)), 256, 0, stream>>>(
        fbf, FF_DIM, prjbf + (size_t)l * C_DIM * FF_DIM, FF_DIM,
        x, C_DIM, FF_DIM, prjb + l * C_DIM, x, C_DIM,
        nw, nb, hbf);
  }
  // logits = LN_f(x) @ wte^T  (counted-vmcnt 256^2; 8 M x 125 N tiles)
  gemm256_k<<<dim3((V_VOCAB / 256) * (T_SEQ / 256)), 512, 131072, stream>>>(
      hbf, C_DIM, wtebf, C_DIM, out, V_VOCAB, C_DIM, T_SEQ / 256);
}

// Round 18
// 499.048 us; speedup vs baseline: 1.0127x; 1.0127x over previous
//
#include <hip/hip_runtime.h>
#include <cstdint>
#include <cstddef>

// ---------------- problem constants ----------------
#define T_SEQ 2048
#define C_DIM 1024
#define H_HEADS 16
#define D_HEAD 64
#define FF_DIM 4096
#define V_VOCAB 32000
#define L_LAYERS 2

typedef unsigned short u16;
typedef short bf16x8 __attribute__((ext_vector_type(8)));
typedef float f32x4 __attribute__((ext_vector_type(4)));

__device__ inline u16 f2bf(float f) {
  unsigned u = __float_as_uint(f);
  u += 0x7fffu + ((u >> 16) & 1u);   // RNE
  return (u16)(u >> 16);
}
__device__ inline float bf2f(u16 h) { return __uint_as_float(((unsigned)h) << 16); }

// ---------------- device arena ----------------
#define OFF_WTEBF   0ULL                    // 32000*1024 bf16
#define OFF_ATTNBF  65536000ULL             // 2*2048*1024 bf16
#define OFF_FCBF    73924608ULL             // 2*4096*1024 bf16
#define OFF_PRJBF   90701824ULL             // 2*1024*4096 bf16
#define OFF_X       107479040ULL            // 2048*1024 f32 (residual stream)
#define OFF_HBF     115867648ULL            // 2048*1024 bf16 (LN out)
#define OFF_QKBF    120061952ULL            // 2048*2048 bf16 (q|k)
#define OFF_VT      128450560ULL            // 16*64*2048 bf16 (V^T per head)
#define OFF_FBF     141033472ULL            // 2048*4096 bf16 (gelu(fc) out)
#define OFF_VWBF    157810688ULL            // 2*16*64*64 bf16 (v_tmp)
#define OFF_PWBF    158072832ULL            // 2*16*64*64 bf16 (proj_tmp)
#define ARENA_BYTES 158334976ULL

__device__ __align__(1024) unsigned char g_arena[ARENA_BYTES];

// ---------------- fused cvt(all weights) + embed+LN1 ------------------------
__global__ void cvt_embed_k(const float4* __restrict__ sw, const float4* __restrict__ s0,
                            const float4* __restrict__ s1, const float4* __restrict__ s2,
                            const float4* __restrict__ s3, const float4* __restrict__ s4,
                            ushort4* __restrict__ dw, ushort4* __restrict__ d0,
                            ushort4* __restrict__ d1, ushort4* __restrict__ d2,
                            ushort4* __restrict__ d3, ushort4* __restrict__ d4,
                            const int* __restrict__ idx, float4* __restrict__ x,
                            const float* __restrict__ lw, const float* __restrict__ lb,
                            ushort4* __restrict__ hout) {
  int blk = blockIdx.x, tid = threadIdx.x;
  if (blk < 52736) {
    int g = blk * 256 + tid;
    const float4* s; ushort4* d; int off;
    if (g < 8192000)       { s = sw; d = dw; off = g; }
    else {
      int g2 = g - 8192000;
      if (g2 < 1048576)      { s = s0; d = d0; off = g2; }
      else if (g2 < 3145728) { s = s1; d = d1; off = g2 - 1048576; }
      else if (g2 < 5242880) { s = s2; d = d2; off = g2 - 3145728; }
      else if (g2 < 5275648) { s = s3; d = d3; off = g2 - 5242880; }
      else                   { s = s4; d = d4; off = g2 - 5275648; }
    }
    float4 v = s[off];
    d[off] = make_ushort4(f2bf(v.x), f2bf(v.y), f2bf(v.z), f2bf(v.w));
  } else {
    int t = blk - 52736;
    int r = idx[t];
    float4 v = sw[(size_t)r * 256 + tid];
    x[(size_t)t * 256 + tid] = v;
    float s = v.x + v.y + v.z + v.w;
    float s2 = v.x * v.x + v.y * v.y + v.z * v.z + v.w * v.w;
    #pragma unroll
    for (int m = 1; m <= 8; m <<= 1) { s += __shfl_xor(s, m); s2 += __shfl_xor(s2, m); }
    int h = tid >> 4;
    float mu = s * (1.f / 64.f), var = s2 * (1.f / 64.f) - mu * mu;
    float rs = rsqrtf(var + 1e-5f) * lw[h], b = lb[h];
    hout[(size_t)t * 256 + tid] =
        make_ushort4(f2bf((v.x - mu) * rs + b), f2bf((v.y - mu) * rs + b),
                     f2bf((v.z - mu) * rs + b), f2bf((v.w - mu) * rs + b));
  }
}

// ---------------- generic swizzled global->LDS staging ----------------
template <int NROWS, int ROWBYTES, int WAVES>
__device__ inline void stage_rows(u16* lds, const u16* __restrict__ g, int ld,
                                  int wid, int lane) {
  constexpr int PASSES = (NROWS * ROWBYTES) / (WAVES * 1024);
  #pragma unroll
  for (int i = 0; i < PASSES; i++) {
    int base = (i * WAVES + wid) * 1024;          // wave-uniform LDS byte base
    int o = base + lane * 16;                     // this lane's linear dest
    int u = o ^ (((o / ROWBYTES) & 7) << 4);      // un-swizzled byte addr
    int row = u / ROWBYTES, colb = u % ROWBYTES;
    const u16* src = g + (size_t)row * ld + (colb >> 1);
    __builtin_amdgcn_global_load_lds((const __attribute__((address_space(1))) void*)src,
                                     (__attribute__((address_space(3))) void*)(lds + base / 2),
                                     16, 0, 0);
  }
}

// single staging pass (pass index i of an 8-wave 256x64 tile stage)
__device__ inline void stage_pass(u16* lds, const u16* __restrict__ g, int ld,
                                  int i, int wid, int lane) {
  int base = (i * 8 + wid) * 1024;
  int o = base + lane * 16;
  int u = o ^ (((o >> 7) & 7) << 4);              // ROWBYTES=128
  int row = u >> 7, colb = u & 127;
  const u16* src = g + (size_t)row * ld + (colb >> 1);
  __builtin_amdgcn_global_load_lds((const __attribute__((address_space(1))) void*)src,
                                   (__attribute__((address_space(3))) void*)(lds + base / 2),
                                   16, 0, 0);
}

// ---------------- flash attention v7.2 (exp2 softmax + T5 setprio) ---------
__global__ __launch_bounds__(256) void flash_k(const u16* __restrict__ qk,
                                               const u16* __restrict__ vt,
                                               const u16* __restrict__ pw,
                                               float* __restrict__ x,
                                               const float* __restrict__ ln2w,
                                               const float* __restrict__ ln2b,
                                               u16* __restrict__ hout) {
  int h = blockIdx.y;
  int q0 = blockIdx.x * 64;
  int tid = threadIdx.x, wid = tid >> 6, lane = tid & 63;
  int g4 = lane >> 4, l15 = lane & 15;
  __shared__ u16 Kl[128 * 64];    // [key][d]    rowbytes 128, swizzled
  __shared__ u16 Vl[64 * 128];    // [d][key]    rowbytes 256, swizzled
  __shared__ u16 Pl[64 * 128];    // [qrow][key] rowbytes 256, wave-private rows
  // exp2-folded constants: exp(v) = exp2(v*log2e)
  float slopeL = exp2f(-0.5f * (float)(h + 1)) * 1.44269504f;

  bf16x8 qf[2];
  const u16* qb = qk + (size_t)(q0 + wid * 16) * 2048 + h * 64;
  #pragma unroll
  for (int kk = 0; kk < 2; kk++)
    qf[kk] = *(const bf16x8*)(qb + (size_t)l15 * 2048 + kk * 32 + g4 * 8);

  float lsum = 0.f;
  f32x4 oacc[4];
  #pragma unroll
  for (int n = 0; n < 4; n++) oacc[n] = (f32x4){0.f, 0.f, 0.f, 0.f};

  const u16* kbase = qk + 1024 + h * 64;
  const u16* vbase = vt + (size_t)h * 64 * T_SEQ;
  int myq = q0 + wid * 16 + l15;

  for (int kt = 0; kt < T_SEQ / 128; kt++) {
    int k0 = kt * 128;
    stage_rows<128, 128, 4>(Kl, kbase + (size_t)k0 * 2048, 2048, wid, lane);
    stage_rows<64, 256, 4>(Vl, vbase + k0, T_SEQ, wid, lane);
    __syncthreads();

    // S^T = K Q^T  (swapped: lane: q=l15, key=n*16+g4*4+i)
    f32x4 s[8];
    #pragma unroll
    for (int n = 0; n < 8; n++) s[n] = (f32x4){0.f, 0.f, 0.f, 0.f};
    __builtin_amdgcn_s_setprio(1);
    #pragma unroll
    for (int kk = 0; kk < 2; kk++) {
      #pragma unroll
      for (int n = 0; n < 8; n++) {
        int r = n * 16 + l15;
        int b = (r * 128 + kk * 64 + g4 * 16) ^ ((r & 7) << 4);
        bf16x8 kf = *(const bf16x8*)((const char*)Kl + b);
        s[n] = __builtin_amdgcn_mfma_f32_16x16x32_bf16(kf, qf[kk], s[n], 0, 0, 0);
      }
    }
    __builtin_amdgcn_s_setprio(0);

    // softmax: p = exp2(s*(0.125*log2e) + slopeL*min(key-q,0) - 8*log2e)
    float fd = (float)(k0 + g4 * 4 - myq);
    int pr = wid * 16 + l15;
    #pragma unroll
    for (int n = 0; n < 8; n++) {
      float p[4];
      #pragma unroll
      for (int i = 0; i < 4; i++) {
        float dj = fd + (float)(n * 16 + i);
        float a2 = fmaf(slopeL, fminf(dj, 0.f), -11.54156036f);
        p[i] = exp2f(fmaf(s[n][i], 0.18033688f, a2));
        lsum += p[i];
      }
      unsigned lo, hi;
      asm("v_cvt_pk_bf16_f32 %0, %1, %2" : "=v"(lo) : "v"(p[0]), "v"(p[1]));
      asm("v_cvt_pk_bf16_f32 %0, %1, %2" : "=v"(hi) : "v"(p[2]), "v"(p[3]));
      int b = (pr * 256 + n * 32 + g4 * 8) ^ ((pr & 7) << 4);
      *(uint2*)((char*)Pl + b) = make_uint2(lo, hi);
    }

    // O += P V
    __builtin_amdgcn_s_setprio(1);
    #pragma unroll
    for (int kk = 0; kk < 4; kk++) {
      int pb = (pr * 256 + kk * 64 + g4 * 16) ^ ((pr & 7) << 4);
      bf16x8 pa = *(const bf16x8*)((const char*)Pl + pb);
      #pragma unroll
      for (int n = 0; n < 4; n++) {
        int d = n * 16 + l15;
        int vb = (d * 256 + kk * 64 + g4 * 16) ^ ((d & 7) << 4);
        bf16x8 vf = *(const bf16x8*)((const char*)Vl + vb);
        oacc[n] = __builtin_amdgcn_mfma_f32_16x16x32_bf16(pa, vf, oacc[n], 0, 0, 0);
      }
    }
    __builtin_amdgcn_s_setprio(0);
    __syncthreads();
  }

  // lsum: keys partitioned across g4 groups -> xor-reduce bits 4,5
  lsum += __shfl_xor(lsum, 16);
  lsum += __shfl_xor(lsum, 32);
  float linv[4];
  #pragma unroll
  for (int i = 0; i < 4; i++) linv[i] = 1.f / __shfl(lsum, g4 * 4 + i);

  // ---- fused head-proj: x[q][h*64+e] += O @ pw[h]^T ----
  stage_rows<64, 128, 4>(Kl, pw + (size_t)h * 4096, 64, wid, lane);
  #pragma unroll
  for (int n = 0; n < 4; n++)
    #pragma unroll
    for (int i = 0; i < 4; i++) {
      int pr = wid * 16 + g4 * 4 + i;
      int b = (pr * 256 + (n * 16 + l15) * 2) ^ ((pr & 7) << 4);
      *(u16*)((char*)Pl + b) = f2bf(oacc[n][i] * linv[i]);
    }
  __syncthreads();   // pw staged (implicit vmcnt drain); own-wave O via lgkm

  f32x4 acc2[4];
  #pragma unroll
  for (int n = 0; n < 4; n++) acc2[n] = (f32x4){0.f, 0.f, 0.f, 0.f};
  #pragma unroll
  for (int kk = 0; kk < 2; kk++) {
    int pr = wid * 16 + l15;
    int ab = (pr * 256 + kk * 64 + g4 * 16) ^ ((pr & 7) << 4);
    bf16x8 af = *(const bf16x8*)((const char*)Pl + ab);
    #pragma unroll
    for (int n = 0; n < 4; n++) {
      int r = n * 16 + l15;
      int wb = (r * 128 + kk * 64 + g4 * 16) ^ ((r & 7) << 4);
      bf16x8 wf = *(const bf16x8*)((const char*)Kl + wb);
      acc2[n] = __builtin_amdgcn_mfma_f32_16x16x32_bf16(af, wf, acc2[n], 0, 0, 0);
    }
  }

  // ---- x RMW + fused LN2 -> hout ----
  float* xb = x + (size_t)(q0 + wid * 16) * C_DIM + h * 64;
  u16* hb = hout + (size_t)(q0 + wid * 16) * C_DIM + h * 64;
  float xv[4][4];
  #pragma unroll
  for (int n = 0; n < 4; n++)
    #pragma unroll
    for (int i = 0; i < 4; i++) {
      size_t o = (size_t)(g4 * 4 + i) * C_DIM + n * 16 + l15;
      float t = xb[o] + acc2[n][i];
      xb[o] = t;
      xv[n][i] = t;
    }
  float lw = ln2w[h], lb = ln2b[h];
  #pragma unroll
  for (int i = 0; i < 4; i++) {
    float s = 0.f, s2 = 0.f;
    #pragma unroll
    for (int n = 0; n < 4; n++) { float t = xv[n][i]; s += t; s2 += t * t; }
    #pragma unroll
    for (int m = 1; m <= 8; m <<= 1) { s += __shfl_xor(s, m); s2 += __shfl_xor(s2, m); }
    float mu = s * (1.f / 64.f), var = s2 * (1.f / 64.f) - mu * mu;
    float rs = rsqrtf(var + 1e-5f) * lw;
    #pragma unroll
    for (int n = 0; n < 4; n++)
      hb[(size_t)(g4 * 4 + i) * C_DIM + n * 16 + l15] = f2bf((xv[n][i] - mu) * rs + lb);
  }
}

// ---------------- 256x256 phase-interleaved GEMM (lm_head) ------------------
// FROZEN at the r16 config (best measured 168-170us). r17's counted-vmcnt
// variant regressed to 182; four schedule variants bracket 168-182 -> the
// structure is scheduling-insensitive (binding constraint is the 1-block/CU
// serial {LDS-read | MFMA | barrier} chain; 2 blocks/CU register-infeasible).
#define ASM_VMCNT0 asm volatile("s_waitcnt vmcnt(0)" ::: "memory")

__global__ __launch_bounds__(512, 1) void gemm256_k(const u16* __restrict__ A, int lda,
                                                    const u16* __restrict__ B, int ldb,
                                                    float* __restrict__ C, int ldc,
                                                    int K, int MT) {
  extern __shared__ u16 sm[];
  u16* lsA = sm;              // [2][256*64] u16
  u16* lsB = sm + 32768;      // [2][256*64] u16
  int tid = threadIdx.x, wid = tid >> 6, lane = tid & 63;
  int g4 = lane >> 4, l15 = lane & 15;
  int wm = wid >> 2, wn = wid & 3;
  int nwg = gridDim.x, lin = blockIdx.x;
  int chunk = nwg >> 3;                       // nwg % 8 == 0 (bijective)
  int w = (lin & 7) * chunk + (lin >> 3);     // XCD gets contiguous chunk
  int by = w % MT, bx = w / MT;               // M-fast -> B-panel reuse
  const u16* Ab = A + (size_t)(by * 256) * lda;
  const u16* Bb = B + (size_t)(bx * 256) * ldb;

  f32x4 acc[8][4];
  #pragma unroll
  for (int m = 0; m < 8; m++)
    #pragma unroll
    for (int n = 0; n < 4; n++) acc[m][n] = (f32x4){0.f, 0.f, 0.f, 0.f};

  int NT = K >> 6;
  stage_rows<256, 128, 8>(lsA, Ab, lda, wid, lane);
  stage_rows<256, 128, 8>(lsB, Bb, ldb, wid, lane);

  for (int t = 0; t < NT; ++t) {
    int cur = t & 1;
    const char* cA = (const char*)(lsA + cur * 16384);
    const char* cB = (const char*)(lsB + cur * 16384);
    u16* nAl = lsA + (cur ^ 1) * 16384;
    u16* nBl = lsB + (cur ^ 1) * 16384;
    const u16* gA = Ab + (t + 1) * 64;
    const u16* gB = Bb + (t + 1) * 64;
    bool pf = (t + 1 < NT);

    ASM_VMCNT0;
    __builtin_amdgcn_s_barrier();
    __builtin_amdgcn_sched_barrier(0);

    bf16x8 bfr[4], af[4];
    #pragma unroll
    for (int ph = 0; ph < 4; ++ph) {
      const int kk = ph >> 1, mh = ph & 1;
      if (mh == 0) {
        #pragma unroll
        for (int n = 0; n < 4; n++) {
          int r = wn * 64 + n * 16 + l15;
          bfr[n] = *(const bf16x8*)(cB + ((r * 128 + kk * 64 + g4 * 16) ^ ((r & 7) << 4)));
        }
      }
      #pragma unroll
      for (int m = 0; m < 4; m++) {
        int r = wm * 128 + mh * 64 + m * 16 + l15;
        af[m] = *(const bf16x8*)(cA + ((r * 128 + kk * 64 + g4 * 16) ^ ((r & 7) << 4)));
      }
      if (pf) {
        if (ph == 0) { stage_pass(nAl, gA, lda, 0, wid, lane);
                       stage_pass(nAl, gA, lda, 1, wid, lane);
                       stage_pass(nBl, gB, ldb, 0, wid, lane); }
        else if (ph == 1) { stage_pass(nAl, gA, lda, 2, wid, lane);
                            stage_pass(nAl, gA, lda, 3, wid, lane);
                            stage_pass(nBl, gB, ldb, 1, wid, lane); }
        else if (ph == 2) { stage_pass(nBl, gB, ldb, 2, wid, lane);
                            stage_pass(nBl, gB, ldb, 3, wid, lane); }
      }
      __builtin_amdgcn_s_setprio(1);
      #pragma unroll
      for (int m = 0; m < 4; m++)
        #pragma unroll
        for (int n = 0; n < 4; n++)
          acc[mh * 4 + m][n] =
              __builtin_amdgcn_mfma_f32_16x16x32_bf16(af[m], bfr[n], acc[mh * 4 + m][n], 0, 0, 0);
      __builtin_amdgcn_s_setprio(0);
      __builtin_amdgcn_s_barrier();
    }
  }

  int gr0 = by * 256 + wm * 128, gc0 = bx * 256 + wn * 64;
  #pragma unroll
  for (int m = 0; m < 8; m++)
    #pragma unroll
    for (int n = 0; n < 4; n++)
      #pragma unroll
      for (int i = 0; i < 4; i++)
        C[(size_t)(gr0 + m * 16 + g4 * 4 + i) * ldc + gc0 + n * 16 + l15] = acc[m][n][i];
}

// ---------------- bf16 NT GEMM body (device fn; LDS passed in) --------------
// EPI: 1=bias+bf16, 2=bf16, 3=bias+gelu+bf16,
//      6=bias+resid+f32 AND fused per-head LN -> hout (needs RN==64)
template <int BM, int BN, int WM, int WN, int EPI, int MT>
__device__ void gemm_body(u16* lsA, u16* lsB,
                          const u16* __restrict__ A, int lda, long long sA,
                          const u16* __restrict__ B, int ldb, long long sB,
                          void* __restrict__ C, int ldc, long long sC,
                          int K, const float* __restrict__ bias,
                          const float* __restrict__ resid, int ldr,
                          const float* __restrict__ lnw, const float* __restrict__ lnb,
                          u16* __restrict__ hout, int lin, int z) {
  constexpr int RM = BM / WM, RN = BN / WN;
  constexpr int MR = RM / 16, NR = RN / 16;
  int tid = threadIdx.x, wid = tid >> 6, lane = tid & 63;
  int wm = wid / WN, wn = wid % WN;
  int by = lin % MT, bx = lin / MT;
  int row0 = by * BM, col0 = bx * BN;
  const u16* Ab = A + (size_t)z * sA + (size_t)row0 * lda;
  const u16* Bb = B + (size_t)z * sB + (size_t)col0 * ldb;
  size_t cz = (size_t)z * sC;

  f32x4 acc[MR][NR];
  #pragma unroll
  for (int m = 0; m < MR; m++)
    #pragma unroll
    for (int n = 0; n < NR; n++) acc[m][n] = (f32x4){0.f, 0.f, 0.f, 0.f};

  for (int k0 = 0; k0 < K; k0 += 64) {
    stage_rows<BM, 128, 4>(lsA, Ab + k0, lda, wid, lane);
    stage_rows<BN, 128, 4>(lsB, Bb + k0, ldb, wid, lane);
    __syncthreads();
    #pragma unroll
    for (int kk = 0; kk < 2; kk++) {
      bf16x8 af[MR], bfr[NR];
      #pragma unroll
      for (int m = 0; m < MR; m++) {
        int r = wm * RM + m * 16 + (lane & 15);
        int bofs = (r * 128 + kk * 64 + ((lane >> 4) * 16)) ^ ((r & 7) << 4);
        af[m] = *(const bf16x8*)((const char*)lsA + bofs);
      }
      #pragma unroll
      for (int n = 0; n < NR; n++) {
        int r = wn * RN + n * 16 + (lane & 15);
        int bofs = (r * 128 + kk * 64 + ((lane >> 4) * 16)) ^ ((r & 7) << 4);
        bfr[n] = *(const bf16x8*)((const char*)lsB + bofs);
      }
      #pragma unroll
      for (int m = 0; m < MR; m++)
        #pragma unroll
        for (int n = 0; n < NR; n++)
          acc[m][n] = __builtin_amdgcn_mfma_f32_16x16x32_bf16(af[m], bfr[n], acc[m][n], 0, 0, 0);
    }
    __syncthreads();
  }

  int rbase = row0 + wm * RM, cbase = col0 + wn * RN;
  if constexpr (EPI == 6) {
    float vv[MR][NR][4];
    #pragma unroll
    for (int m = 0; m < MR; m++)
      #pragma unroll
      for (int n = 0; n < NR; n++)
        #pragma unroll
        for (int i = 0; i < 4; i++) {
          int gr = rbase + m * 16 + ((lane >> 4) * 4) + i;
          int gc = cbase + n * 16 + (lane & 15);
          float v = acc[m][n][i] + bias[gc] + resid[(size_t)gr * ldr + gc];
          vv[m][n][i] = v;
          ((float*)C)[(size_t)gr * ldc + gc] = v;
        }
    int h = cbase >> 6;
    float lw = lnw[h], lb = lnb[h];
    #pragma unroll
    for (int m = 0; m < MR; m++)
      #pragma unroll
      for (int i = 0; i < 4; i++) {
        float s = 0.f, s2 = 0.f;
        #pragma unroll
        for (int n = 0; n < NR; n++) { float t = vv[m][n][i]; s += t; s2 += t * t; }
        #pragma unroll
        for (int msk = 1; msk <= 8; msk <<= 1) { s += __shfl_xor(s, msk); s2 += __shfl_xor(s2, msk); }
        float mu = s * (1.f / 64.f), var = s2 * (1.f / 64.f) - mu * mu;
        float rs = rsqrtf(var + 1e-5f) * lw;
        int gr = rbase + m * 16 + ((lane >> 4) * 4) + i;
        #pragma unroll
        for (int n = 0; n < NR; n++) {
          int gc = cbase + n * 16 + (lane & 15);
          hout[(size_t)gr * C_DIM + gc] = f2bf((vv[m][n][i] - mu) * rs + lb);
        }
      }
  } else {
    #pragma unroll
    for (int m = 0; m < MR; m++)
      #pragma unroll
      for (int n = 0; n < NR; n++)
        #pragma unroll
        for (int i = 0; i < 4; i++) {
          int gr = rbase + m * 16 + ((lane >> 4) * 4) + i;
          int gc = cbase + n * 16 + (lane & 15);
          size_t idx = cz + (size_t)gr * ldc + gc;
          float v = acc[m][n][i];
          if constexpr (EPI == 1) {
            v += bias[gc];
            ((u16*)C)[idx] = f2bf(v);
          } else if constexpr (EPI == 2) {
            ((u16*)C)[idx] = f2bf(v);
          } else if constexpr (EPI == 3) {
            v += bias[gc];
            v = 0.5f * v * (1.f + erff(v * 0.70710678118654752f));
            ((u16*)C)[idx] = f2bf(v);
          }
        }
  }
}

// standalone GEMM wrapper (M-fast 1D grid + bijective XCD chunk, z=0)
template <int BM, int BN, int WM, int WN, int EPI, int MT>
__global__ void gemm_nt(const u16* __restrict__ A, int lda,
                        const u16* __restrict__ B, int ldb,
                        void* __restrict__ C, int ldc,
                        int K, const float* __restrict__ bias,
                        const float* __restrict__ resid, int ldr,
                        const float* __restrict__ lnw, const float* __restrict__ lnb,
                        u16* __restrict__ hout) {
  __shared__ u16 lsA[BM * 64];
  __shared__ u16 lsB[BN * 64];
  int nwg = gridDim.x, l0 = blockIdx.x;
  int chunk = nwg >> 3;
  int lin = (l0 & 7) * chunk + (l0 >> 3);
  gemm_body<BM, BN, WM, WN, EPI, MT>(lsA, lsB, A, lda, 0, B, ldb, 0, C, ldc, 0,
                                     K, bias, resid, ldr, lnw, lnb, hout, lin, 0);
}

// merged qk + vt launch: blocks [0,512) qk GEMM, [512,768) per-head vt GEMM
__global__ void qkv_k(const u16* __restrict__ hbf, const u16* __restrict__ attw,
                      const float* __restrict__ attb, u16* __restrict__ qkbf,
                      const u16* __restrict__ vw, u16* __restrict__ vt) {
  __shared__ u16 lsA[64 * 64];
  __shared__ u16 lsB[128 * 64];
  int l0 = blockIdx.x;
  if (l0 < 512) {
    int lin = (l0 & 7) * 64 + (l0 >> 3);          // XCD chunk over 512
    gemm_body<64, 128, 2, 2, 1, 32>(lsA, lsB, hbf, C_DIM, 0, attw, C_DIM, 0,
                                    qkbf, 2 * C_DIM, 0, C_DIM, attb, nullptr, 0,
                                    nullptr, nullptr, nullptr, lin, 0);
  } else {
    int i2 = l0 - 512;                             // 256 blocks: 16 tiles x 16 heads
    gemm_body<64, 128, 2, 2, 2, 1>(lsA, lsB, vw, 64, 4096, hbf, C_DIM, 64,
                                   vt, T_SEQ, (long long)64 * T_SEQ, 64,
                                   nullptr, nullptr, 0, nullptr, nullptr, nullptr,
                                   i2 & 15, i2 >> 4);
  }
}

// ---------------- host launch ----------------
extern "C" void kernel_launch(void* const* d_in, const int* in_sizes, int n_in,
                              void* d_out, int out_size, void* d_ws, size_t ws_size,
                              hipStream_t stream) {
  (void)in_sizes; (void)n_in; (void)out_size; (void)d_ws; (void)ws_size;
  const int*   idx    = (const int*)d_in[0];
  const float* wte    = (const float*)d_in[1];
  const float* ln1w   = (const float*)d_in[2];
  const float* ln1b   = (const float*)d_in[3];
  const float* ln2w   = (const float*)d_in[4];
  const float* ln2b   = (const float*)d_in[5];
  const float* lnfw   = (const float*)d_in[6];
  const float* lnfb   = (const float*)d_in[7];
  const float* attw   = (const float*)d_in[8];
  const float* attb   = (const float*)d_in[9];
  const float* vtmp   = (const float*)d_in[10];
  const float* ptmp   = (const float*)d_in[11];
  const float* fcw    = (const float*)d_in[12];
  const float* fcb    = (const float*)d_in[13];
  const float* prjw   = (const float*)d_in[14];
  const float* prjb   = (const float*)d_in[15];
  float* out = (float*)d_out;

  unsigned char* ar = nullptr;
  (void)hipGetSymbolAddress((void**)&ar, HIP_SYMBOL(g_arena));
  u16*   wtebf  = (u16*)(ar + OFF_WTEBF);
  u16*   attnbf = (u16*)(ar + OFF_ATTNBF);
  u16*   fcbf   = (u16*)(ar + OFF_FCBF);
  u16*   prjbf  = (u16*)(ar + OFF_PRJBF);
  float* x      = (float*)(ar + OFF_X);
  u16*   hbf    = (u16*)(ar + OFF_HBF);
  u16*   qkbf   = (u16*)(ar + OFF_QKBF);
  u16*   vt     = (u16*)(ar + OFF_VT);
  u16*   fbf    = (u16*)(ar + OFF_FBF);
  u16*   vwbf   = (u16*)(ar + OFF_VWBF);
  u16*   pwbf   = (u16*)(ar + OFF_PWBF);

  (void)hipFuncSetAttribute((const void*)gemm256_k,
                            hipFuncAttributeMaxDynamicSharedMemorySize, 131072);

  // weight cvt + embed+LN1 in ONE launch (embed blocks appended after cvt)
  cvt_embed_k<<<dim3(52736 + T_SEQ), 256, 0, stream>>>(
      (const float4*)wte, (const float4*)attw, (const float4*)fcw,
      (const float4*)prjw, (const float4*)vtmp, (const float4*)ptmp,
      (ushort4*)wtebf, (ushort4*)attnbf, (ushort4*)fcbf,
      (ushort4*)prjbf, (ushort4*)vwbf, (ushort4*)pwbf,
      idx, (float4*)x, ln1w, ln1b, (ushort4*)hbf);

  for (int l = 0; l < L_LAYERS; l++) {
    // qk GEMM + per-head vt GEMM in one launch (768 blocks, 3/CU)
    qkv_k<<<dim3(768), 256, 0, stream>>>(
        hbf, attnbf + (size_t)l * 2 * C_DIM * C_DIM, attb + l * 2 * C_DIM, qkbf,
        vwbf + (size_t)l * H_HEADS * 4096, vt);
    // flash attention + head-proj (x +=) + LN2 -> hbf
    flash_k<<<dim3(T_SEQ / 64, H_HEADS), 256, 0, stream>>>(
        qkbf, vt, pwbf + (size_t)l * H_HEADS * 4096, x,
        ln2w + l * H_HEADS, ln2b + l * H_HEADS, hbf);
    // f = gelu(LN2(x) @ fc_w^T + fc_b) -> bf16  (1024 blocks, 4/CU)
    gemm_nt<64, 128, 2, 2, 3, 32><<<dim3((FF_DIM / 128) * (T_SEQ / 64)), 256, 0, stream>>>(
        hbf, C_DIM, fcbf + (size_t)l * FF_DIM * C_DIM, C_DIM,
        fbf, FF_DIM, C_DIM, fcb + l * FF_DIM, nullptr, 0,
        nullptr, nullptr, nullptr);
    // x = x + f @ proj_w^T + proj_b  AND fused LN (next LN1 / LNf)
    const float* nw = (l + 1 < L_LAYERS) ? ln1w + (l + 1) * H_HEADS : lnfw;
    const float* nb = (l + 1 < L_LAYERS) ? ln1b + (l + 1) * H_HEADS : lnfb;
    gemm_nt<32, 128, 2, 2, 6, 64><<<dim3((C_DIM / 128) * (T_SEQ / 32)), 256, 0, stream>>>(
        fbf, FF_DIM, prjbf + (size_t)l * C_DIM * FF_DIM, FF_DIM,
        x, C_DIM, FF_DIM, prjb + l * C_DIM, x, C_DIM,
        nw, nb, hbf);
  }
  // logits = LN_f(x) @ wte^T  (phase-interleaved 256^2; 8 M x 125 N tiles)
  gemm256_k<<<dim3((V_VOCAB / 256) * (T_SEQ / 256)), 512, 131072, stream>>>(
      hbf, C_DIM, wtebf, C_DIM, out, V_VOCAB, C_DIM, T_SEQ / 256);
}